// Round 12
// baseline (243.225 us; speedup 1.0000x reference)
//
#include <hip/hip_runtime.h>

#define NPT   4096
#define KNN_K 16
#define EPSV  1e-5f

// ---- ws float layout ----
#define W1T_OFF 4352               // [64][64]  (ic-major)
#define B1_OFF  8448               // [64]
#define W2T_OFF 8512               // [64][128] (ic-major)
#define B2_OFF  16704              // [128]
#define IDX_OFF 16832              // int[4*4096*16]
#define P_OFF   344512             // float[16384][64]  P = W0p*pts + W0x*xyz + b0
#define Q_OFF   1393088            // float[16384][64]  Q = W0x*xyz

typedef unsigned long long ull;

__device__ __forceinline__ ull minu64(ull a, ull b) { return a < b ? a : b; }
__device__ __forceinline__ ull maxu64(ull a, ull b) { return a > b ? a : b; }

__device__ __forceinline__ ull bitonic_sort64(ull v, int lane) {
#pragma unroll
  for (int k = 2; k <= 64; k <<= 1) {
#pragma unroll
    for (int j = k >> 1; j > 0; j >>= 1) {
      ull o = __shfl_xor(v, j);
      bool lower = (lane & j) == 0;
      bool up = (lane & k) == 0;
      v = (lower == up) ? minu64(v, o) : maxu64(v, o);
    }
  }
  return v;
}

__device__ __forceinline__ ull bitonic_merge64(ull v, int lane) {
#pragma unroll
  for (int j = 32; j > 0; j >>= 1) {
    ull o = __shfl_xor(v, j);
    v = ((lane & j) == 0) ? minu64(v, o) : maxu64(v, o);
  }
  return v;
}

// One filter/flush step for one query against one lane-resident candidate.
// All state (thresh_hi, cnt) is wave-uniform; branches are wave-uniform.
__device__ __forceinline__ void filter_step(float4 q, float4 c, unsigned idx32,
                                            unsigned& thresh_hi, int& cnt,
                                            ull& R, ull* buf, int lane) {
  float dot = __fadd_rn(__fadd_rn(__fmul_rn(q.x, c.x), __fmul_rn(q.y, c.y)),
                        __fmul_rn(q.z, c.z));
  float d2 = __fsub_rn(__fadd_rn(q.w, c.w), __fmul_rn(2.0f, dot));
  unsigned bits = __float_as_uint(d2);
  unsigned fk = bits ^ (0x80000000u | (unsigned)((int)bits >> 31));
  bool pred = fk <= thresh_hi;     // superset of exact u64 test; flush is exact
  ull mask = __ballot(pred);
  if (mask) {
    int pos = cnt + (int)__builtin_amdgcn_mbcnt_hi(
                        (unsigned)(mask >> 32),
                        __builtin_amdgcn_mbcnt_lo((unsigned)mask, 0u));
    if (pred) buf[pos] = ((ull)fk << 32) | idx32;
    cnt += __popcll(mask);
    if (cnt >= 64) {
      ull v = buf[lane];
      v = bitonic_sort64(v, lane);
      ull vr = __shfl(v, 63 - lane);
      R = minu64(R, vr);
      R = bitonic_merge64(R, lane);
      thresh_hi = (unsigned)__shfl((int)(unsigned)(R >> 32), 15);
      cnt -= 64;
      if (lane < cnt) {
        ull tmp = buf[64 + lane];
        buf[lane] = tmp;
      }
    }
  }
}

__device__ __forceinline__ ull final_flush(ull R, int cnt, ull* buf, int lane) {
  ull v = (lane < cnt) ? buf[lane] : ~0ull;
  v = bitonic_sort64(v, lane);
  ull vr = __shfl(v, 63 - lane);
  R = minu64(R, vr);
  return bitonic_merge64(R, lane);
}

// MEGA kernel v14: knn now 4 QUERIES PER WAVE (1024 blocks, 16 q/block) — one
// register-direct candidate load feeds four filter pipelines (R9->R10 showed
// candidate delivery dominates knn; per-CU load traffic halves again vs 2q).
//   blocks [0,1024):    KNN (dispatched FIRST; 4/CU resident, pq co-resident)
//   blocks [1024,3072): P/Q, 2 points/wave
//   blocks [3072,3121): W1/W2/bias fold for mlp
__global__ __launch_bounds__(256) void mega_kernel(
    const float* __restrict__ xyz, const float* __restrict__ points,
    const float* __restrict__ w0, const float* __restrict__ b0, const float* __restrict__ g0,
    const float* __restrict__ be0, const float* __restrict__ rm0, const float* __restrict__ rv0,
    const float* __restrict__ w1, const float* __restrict__ b1, const float* __restrict__ g1,
    const float* __restrict__ be1, const float* __restrict__ rm1, const float* __restrict__ rv1,
    const float* __restrict__ w2, const float* __restrict__ b2, const float* __restrict__ g2,
    const float* __restrict__ be2, const float* __restrict__ rm2, const float* __restrict__ rv2,
    float* __restrict__ ws, int* __restrict__ knnOut) {
  __shared__ __align__(16) unsigned char smem[20480];  // knn: 16K flush bufs; pq: 17.2K w0
  int blk = blockIdx.x;
  int tid = threadIdx.x;

  if (blk < 1024) {
    // ------------ KNN: 4 queries/wave, register-direct candidates ---------
    ull* bufb = (ull*)smem;                       // [4 waves][4 queries][128]
    int lane = tid & 63, w = tid >> 6;
    int b = blk >> 8;                             // 256 blocks per batch
    int n0 = ((blk & 255) << 4) + (w << 2);
    const float* xb = xyz + (size_t)b * NPT * 3;
    ull* buf0 = bufb + w * 512;
    ull* buf1 = buf0 + 128;
    ull* buf2 = buf0 + 256;
    ull* buf3 = buf0 + 384;

    float4 q0, q1, q2, q3;
    {
      const float* qp = xb + n0 * 3;
      float x0 = qp[0], y0 = qp[1], z0 = qp[2];
      float x1 = qp[3], y1 = qp[4], z1 = qp[5];
      float x2 = qp[6], y2 = qp[7], z2 = qp[8];
      float x3 = qp[9], y3 = qp[10], z3 = qp[11];
      q0 = make_float4(x0, y0, z0,
          __fadd_rn(__fadd_rn(__fmul_rn(x0, x0), __fmul_rn(y0, y0)), __fmul_rn(z0, z0)));
      q1 = make_float4(x1, y1, z1,
          __fadd_rn(__fadd_rn(__fmul_rn(x1, x1), __fmul_rn(y1, y1)), __fmul_rn(z1, z1)));
      q2 = make_float4(x2, y2, z2,
          __fadd_rn(__fadd_rn(__fmul_rn(x2, x2), __fmul_rn(y2, y2)), __fmul_rn(z2, z2)));
      q3 = make_float4(x3, y3, z3,
          __fadd_rn(__fadd_rn(__fmul_rn(x3, x3), __fmul_rn(y3, y3)), __fmul_rn(z3, z3)));
    }
    ull R0 = ~0ull, R1 = ~0ull, R2 = ~0ull, R3 = ~0ull;
    unsigned th0 = 0xFFFFFFFFu, th1 = 0xFFFFFFFFu, th2 = 0xFFFFFFFFu, th3 = 0xFFFFFFFFu;
    int cnt0 = 0, cnt1 = 0, cnt2 = 0, cnt3 = 0;

    // iter-0 preload (lane-resident candidate)
    float cx = xb[3 * lane], cy = xb[3 * lane + 1], cz = xb[3 * lane + 2];
#pragma unroll 1
    for (int g = 0; g < NPT; g += 64) {
      // prefetch next group (wrapped on last iter; values unused)
      int ni = 3 * ((g + 64 + lane) & (NPT - 1));
      float nx = xb[ni], ny = xb[ni + 1], nz = xb[ni + 2];
      float csq = __fadd_rn(__fadd_rn(__fmul_rn(cx, cx), __fmul_rn(cy, cy)),
                            __fmul_rn(cz, cz));
      float4 c = make_float4(cx, cy, cz, csq);
      unsigned idx32 = (unsigned)(g + lane);
      filter_step(q0, c, idx32, th0, cnt0, R0, buf0, lane);
      filter_step(q1, c, idx32, th1, cnt1, R1, buf1, lane);
      filter_step(q2, c, idx32, th2, cnt2, R2, buf2, lane);
      filter_step(q3, c, idx32, th3, cnt3, R3, buf3, lane);
      cx = nx; cy = ny; cz = nz;
    }
    R0 = final_flush(R0, cnt0, buf0, lane);
    R1 = final_flush(R1, cnt1, buf1, lane);
    R2 = final_flush(R2, cnt2, buf2, lane);
    R3 = final_flush(R3, cnt3, buf3, lane);
    if (lane < KNN_K) {
      knnOut[(b * NPT + n0 + 0) * KNN_K + lane] = (int)(unsigned)(R0 & 0xFFFFFFFFull);
      knnOut[(b * NPT + n0 + 1) * KNN_K + lane] = (int)(unsigned)(R1 & 0xFFFFFFFFull);
      knnOut[(b * NPT + n0 + 2) * KNN_K + lane] = (int)(unsigned)(R2 & 0xFFFFFFFFull);
      knnOut[(b * NPT + n0 + 3) * KNN_K + lane] = (int)(unsigned)(R3 & 0xFFFFFFFFull);
    }
    return;
  }

  if (blk < 3072) {
    // ---------------- P/Q precompute: 2 points per wave ------------------
    float* wlds = (float*)smem;                   // [64*67] folded w0
    for (int j = tid; j < 4288; j += 256) {
      int r = j / 67;
      float s = g0[r] * rsqrtf(rv0[r] + EPSV);
      wlds[j] = __fmul_rn(w0[j], s);
    }
    __syncthreads();
    int oc = tid & 63;
    int base = (blk - 1024) * 8 + (tid >> 6);
    float s = g0[oc] * rsqrtf(rv0[oc] + EPSV);
    float b0f = (b0[oc] - rm0[oc]) * s + be0[oc];
    const float* wrow = wlds + oc * 67;           // stride-67 -> 2-way bank (free)
#pragma unroll 1
    for (int pt = 0; pt < 2; ++pt) {
      int i = base + pt * 4;
      float x = xyz[i * 3], y = xyz[i * 3 + 1], z = xyz[i * 3 + 2];
      float qacc = wrow[0] * x;
      qacc = fmaf(wrow[1], y, qacc);
      qacc = fmaf(wrow[2], z, qacc);
      float acc = b0f + qacc;
      const float* prow = points + (size_t)i * 64;
#pragma unroll 4
      for (int c = 0; c < 64; ++c) acc = fmaf(wrow[3 + c], prow[c], acc);
      ws[P_OFF + (size_t)i * 64 + oc] = acc;
      ws[Q_OFF + (size_t)i * 64 + oc] = qacc;
    }
    return;
  }

  // ---------------- weight fold for mlp (W1T/B1/W2T/B2) ------------------
  {
    int i = (blk - 3072) * 256 + tid + 4352;
    if (i < 8448) {
      int j = i - 4352; int oc = j & 63, ic = j >> 6;
      float s = g1[oc] * rsqrtf(rv1[oc] + EPSV);
      ws[i] = w1[oc * 64 + ic] * s;
    } else if (i < 8512) {
      int oc = i - 8448;
      float s = g1[oc] * rsqrtf(rv1[oc] + EPSV);
      ws[i] = (b1[oc] - rm1[oc]) * s + be1[oc];
    } else if (i < 16704) {
      int j = i - 8512; int ic = j >> 7, oc = j & 127;
      float s = g2[oc] * rsqrtf(rv2[oc] + EPSV);
      ws[i] = w2[oc * 64 + ic] * s;               // w2t [ic][oc]
    } else if (i < 16832) {
      int oc = i - 16704;
      float s = g2[oc] * rsqrtf(rv2[oc] + EPSV);
      ws[i] = (b2[oc] - rm2[oc]) * s + be2[oc];
    }
  }
}

// MLP v14: v8 structure (40 KB LDS, 4 blocks/CU) + explicit DISTANCE-2
// software pipeline in the GEMM inner loop. R11 evidence: mlp invariant at
// ~89.5us across occupancy/tiling/barriers with VGPR=52 -> compiler reloads
// LDS just-in-time, leaking ~60cyc/iter of ds_read latency. Ping-pong-pong
// named registers (static indices under full unroll, rule-#20-safe) force
// 2 iterations of loads in flight. FMA accumulation order per output is
// unchanged (bias + ic 0..63 sequential) -> bit-identical results.
__global__ __launch_bounds__(256, 4) void mlp_kernel(
    const float* __restrict__ wbuf, const int* __restrict__ knn,
    float* __restrict__ out) {
  __shared__ __align__(16) float Ash[64 * 128];   // 32 KB [ic][p]
  __shared__ __align__(16) float Wsh[32 * 64];    // 8 KB chunk [icLocal][oc]
  int tid = threadIdx.x;
  int qblk = blockIdx.x << 3;                     // 8 flat queries per block

  const float4* w1g = (const float4*)(wbuf + W1T_OFF);   // [64][16 f4]
  const float4* w2g = (const float4*)(wbuf + W2T_OFF);   // [64][32 f4]
  float4* wl = (float4*)Wsh;

  // W2 chunk (pass p, ic-half h) entry e in [0,512): row 32h+(e>>4), colf4 16p+(e&15)
#define W2IDX(e, p, h) ((((h) << 5) + ((e) >> 4)) * 32 + ((p) << 4) + ((e) & 15))

  // ---- preload W1a ----
  float4 s0 = w1g[tid];
  float4 s1 = w1g[256 + tid];

  // ---- h0: pair p = tid&127, ic-half = tid>>7 ----
  {
    int p = tid & 127, half = tid >> 7;
    int q = qblk + (p >> 4);
    int k = p & 15;
    int src = knn[q * KNN_K + k];                 // coalesced across 128 threads
    int srow = (q & ~(NPT - 1)) + src;
    const float4* Pp = (const float4*)(wbuf + P_OFF + (size_t)srow * 64 + half * 32);
    const float4* Qp = (const float4*)(wbuf + Q_OFF + (size_t)q * 64 + half * 32);
#pragma unroll
    for (int j = 0; j < 8; ++j) {
      float4 pv = Pp[j];
      float4 qv = Qp[j];
      int ic = half * 32 + j * 4;
      Ash[(ic + 0) * 128 + p] = fmaxf(pv.x - qv.x, 0.0f);
      Ash[(ic + 1) * 128 + p] = fmaxf(pv.y - qv.y, 0.0f);
      Ash[(ic + 2) * 128 + p] = fmaxf(pv.z - qv.z, 0.0f);
      Ash[(ic + 3) * 128 + p] = fmaxf(pv.w - qv.w, 0.0f);
    }
  }
  // write W1a; preload W1b
  wl[tid] = s0; wl[256 + tid] = s1;
  s0 = w1g[512 + tid]; s1 = w1g[768 + tid];
  __syncthreads();                                 // S1: h0 + W1a visible

  int og = tid & 7, pg = tid >> 3;                 // 32 pgrp x 8 ogrp
  const float* Arow = Ash + 4 * pg;
  const float* Wrow = Wsh + 8 * og;
  float acc[4][8];                                 // [pair][oc]

  // distance-2 software-pipelined 32-ic GEMM: loads for ic+2 issue before
  // the FMAs of ic; all register names static after full unroll.
#define LD_A(R0, i)  (*(const float4*)(Arow + ((R0) + (i)) * 128))
#define LD_W0(i)     (*(const float4*)(Wrow + (i) * 64))
#define LD_W1(i)     (*(const float4*)(Wrow + (i) * 64 + 4))
#define GEMM32(R0)                                                        \
  {                                                                       \
    float4 aA = LD_A(R0, 0), wA0 = LD_W0(0), wA1 = LD_W1(0);              \
    float4 aB = LD_A(R0, 1), wB0 = LD_W0(1), wB1 = LD_W1(1);              \
    _Pragma("unroll")                                                     \
    for (int ic = 0; ic < 32; ++ic) {                                     \
      int nx = (ic + 2 <= 31) ? ic + 2 : 31;                              \
      float4 aN = LD_A(R0, nx);                                           \
      float4 wN0 = LD_W0(nx);                                             \
      float4 wN1 = LD_W1(nx);                                             \
      float av[4] = {aA.x, aA.y, aA.z, aA.w};                             \
      float wv[8] = {wA0.x, wA0.y, wA0.z, wA0.w, wA1.x, wA1.y, wA1.z, wA1.w};\
      _Pragma("unroll")                                                   \
      for (int ii = 0; ii < 4; ++ii)                                      \
        _Pragma("unroll")                                                 \
        for (int jj = 0; jj < 8; ++jj) acc[ii][jj] = fmaf(av[ii], wv[jj], acc[ii][jj]); \
      aA = aB; wA0 = wB0; wA1 = wB1;                                      \
      aB = aN; wB0 = wN0; wB1 = wN1;                                      \
    }                                                                     \
  }

  // ---- layer 1 ----
  {
    float4 b0v = *(const float4*)(wbuf + B1_OFF + 8 * og);
    float4 b1v = *(const float4*)(wbuf + B1_OFF + 8 * og + 4);
    float bj[8] = {b0v.x, b0v.y, b0v.z, b0v.w, b1v.x, b1v.y, b1v.z, b1v.w};
#pragma unroll
    for (int i = 0; i < 4; ++i)
#pragma unroll
      for (int j = 0; j < 8; ++j) acc[i][j] = bj[j];
  }
  GEMM32(0)                                        // W1a: ic 0..31
  __syncthreads();                                 // S2: W1a reads done
  wl[tid] = s0; wl[256 + tid] = s1;                // write W1b
  s0 = w2g[W2IDX(tid, 0, 0)]; s1 = w2g[W2IDX(tid + 256, 0, 0)];
  __syncthreads();                                 // S3: W1b visible
  GEMM32(32)                                       // W1b: ic 32..63
  __syncthreads();                                 // S4: all Ash(h0)+W1b reads done

  // h1 -> A[oc][p] (write throughput-limited, once per layer: accepted)
#pragma unroll
  for (int j = 0; j < 8; ++j) {
    int oc = 8 * og + j;
    *(float4*)(Ash + oc * 128 + 4 * pg) =
        make_float4(fmaxf(acc[0][j], 0.0f), fmaxf(acc[1][j], 0.0f),
                    fmaxf(acc[2][j], 0.0f), fmaxf(acc[3][j], 0.0f));
  }
  // stage W2p0a from regs; preload W2p0b
  wl[tid] = s0; wl[256 + tid] = s1;
  s0 = w2g[W2IDX(tid, 0, 1)]; s1 = w2g[W2IDX(tid + 256, 0, 1)];
  __syncthreads();                                 // S5: h1 + W2p0a visible

  int qout = qblk + (pg >> 2);
  float* obase = out + (size_t)qout * 128 + 8 * og;

  // ---- layer 2 pass 0 (oc 0..63) ----
  {
    float4 b0v = *(const float4*)(wbuf + B2_OFF + 8 * og);
    float4 b1v = *(const float4*)(wbuf + B2_OFF + 8 * og + 4);
    float bj[8] = {b0v.x, b0v.y, b0v.z, b0v.w, b1v.x, b1v.y, b1v.z, b1v.w};
#pragma unroll
    for (int i = 0; i < 4; ++i)
#pragma unroll
      for (int j = 0; j < 8; ++j) acc[i][j] = bj[j];
  }
  GEMM32(0)                                        // W2p0a: ic 0..31
  __syncthreads();                                 // S6
  wl[tid] = s0; wl[256 + tid] = s1;                // write W2p0b
  s0 = w2g[W2IDX(tid, 1, 0)]; s1 = w2g[W2IDX(tid + 256, 1, 0)];
  __syncthreads();                                 // S7
  GEMM32(32)                                       // W2p0b: ic 32..63
  {
    float m[8];
#pragma unroll
    for (int j = 0; j < 8; ++j) {
      float v = fmaxf(fmaxf(acc[0][j], acc[1][j]), fmaxf(acc[2][j], acc[3][j]));
      v = fmaxf(v, 0.0f);
      v = fmaxf(v, __shfl_xor(v, 8));              // pg bit 0
      m[j] = fmaxf(v, __shfl_xor(v, 16));          // pg bit 1
    }
    if ((pg & 3) == 0) {
      *(float4*)(obase)     = make_float4(m[0], m[1], m[2], m[3]);
      *(float4*)(obase + 4) = make_float4(m[4], m[5], m[6], m[7]);
    }
  }
  __syncthreads();                                 // S8
  wl[tid] = s0; wl[256 + tid] = s1;                // write W2p1a
  s0 = w2g[W2IDX(tid, 1, 1)]; s1 = w2g[W2IDX(tid + 256, 1, 1)];
  __syncthreads();                                 // S9

  // ---- layer 2 pass 1 (oc 64..127) ----
  {
    float4 b0v = *(const float4*)(wbuf + B2_OFF + 64 + 8 * og);
    float4 b1v = *(const float4*)(wbuf + B2_OFF + 64 + 8 * og + 4);
    float bj[8] = {b0v.x, b0v.y, b0v.z, b0v.w, b1v.x, b1v.y, b1v.z, b1v.w};
#pragma unroll
    for (int i = 0; i < 4; ++i)
#pragma unroll
      for (int j = 0; j < 8; ++j) acc[i][j] = bj[j];
  }
  GEMM32(0)                                        // W2p1a: ic 0..31
  __syncthreads();                                 // S10
  wl[tid] = s0; wl[256 + tid] = s1;                // write W2p1b
  __syncthreads();                                 // S11
  GEMM32(32)                                       // W2p1b: ic 32..63
  {
    float m[8];
#pragma unroll
    for (int j = 0; j < 8; ++j) {
      float v = fmaxf(fmaxf(acc[0][j], acc[1][j]), fmaxf(acc[2][j], acc[3][j]));
      v = fmaxf(v, 0.0f);
      v = fmaxf(v, __shfl_xor(v, 8));
      m[j] = fmaxf(v, __shfl_xor(v, 16));
    }
    if ((pg & 3) == 0) {
      *(float4*)(obase + 64)     = make_float4(m[0], m[1], m[2], m[3]);
      *(float4*)(obase + 64 + 4) = make_float4(m[4], m[5], m[6], m[7]);
    }
  }
#undef GEMM32
#undef LD_A
#undef LD_W0
#undef LD_W1
#undef W2IDX
}

extern "C" void kernel_launch(void* const* d_in, const int* in_sizes, int n_in,
                              void* d_out, int out_size, void* d_ws, size_t ws_size,
                              hipStream_t stream) {
  const float* xyz    = (const float*)d_in[0];
  const float* points = (const float*)d_in[1];
  float* wsF = (float*)d_ws;
  int* idxBuf = (int*)(wsF + IDX_OFF);

  mega_kernel<<<3121, 256, 0, stream>>>(
      xyz, points,
      (const float*)d_in[2],  (const float*)d_in[3],  (const float*)d_in[4],
      (const float*)d_in[5],  (const float*)d_in[6],  (const float*)d_in[7],
      (const float*)d_in[8],  (const float*)d_in[9],  (const float*)d_in[10],
      (const float*)d_in[11], (const float*)d_in[12], (const float*)d_in[13],
      (const float*)d_in[14], (const float*)d_in[15], (const float*)d_in[16],
      (const float*)d_in[17], (const float*)d_in[18], (const float*)d_in[19],
      wsF, idxBuf);
  mlp_kernel<<<2048, 256, 0, stream>>>(wsF, idxBuf, (float*)d_out);
}

// Round 13
// 230.837 us; speedup vs baseline: 1.0537x; 1.0537x over previous
//
#include <hip/hip_runtime.h>

#define NPT   4096
#define KNN_K 16
#define EPSV  1e-5f

// ---- ws float layout ----
#define W1T_OFF 4352               // [64][64]  (ic-major)
#define B1_OFF  8448               // [64]
#define W2T_OFF 8512               // [64][128] (ic-major)
#define B2_OFF  16704              // [128]
#define IDX_OFF 16832              // int[4*4096*16]
#define P_OFF   344512             // float[16384][64]  P = W0p*pts + W0x*xyz + b0
#define Q_OFF   1393088            // float[16384][64]  Q = W0x*xyz

typedef unsigned long long ull;

__device__ __forceinline__ ull minu64(ull a, ull b) { return a < b ? a : b; }
__device__ __forceinline__ ull maxu64(ull a, ull b) { return a > b ? a : b; }

__device__ __forceinline__ ull bitonic_sort64(ull v, int lane) {
#pragma unroll
  for (int k = 2; k <= 64; k <<= 1) {
#pragma unroll
    for (int j = k >> 1; j > 0; j >>= 1) {
      ull o = __shfl_xor(v, j);
      bool lower = (lane & j) == 0;
      bool up = (lane & k) == 0;
      v = (lower == up) ? minu64(v, o) : maxu64(v, o);
    }
  }
  return v;
}

__device__ __forceinline__ ull bitonic_merge64(ull v, int lane) {
#pragma unroll
  for (int j = 32; j > 0; j >>= 1) {
    ull o = __shfl_xor(v, j);
    v = ((lane & j) == 0) ? minu64(v, o) : maxu64(v, o);
  }
  return v;
}

// One filter/flush step for one query against one lane-resident candidate.
// All state (thresh_hi, cnt) is wave-uniform; branches are wave-uniform.
__device__ __forceinline__ void filter_step(float4 q, float4 c, unsigned idx32,
                                            unsigned& thresh_hi, int& cnt,
                                            ull& R, ull* buf, int lane) {
  float dot = __fadd_rn(__fadd_rn(__fmul_rn(q.x, c.x), __fmul_rn(q.y, c.y)),
                        __fmul_rn(q.z, c.z));
  float d2 = __fsub_rn(__fadd_rn(q.w, c.w), __fmul_rn(2.0f, dot));
  unsigned bits = __float_as_uint(d2);
  unsigned fk = bits ^ (0x80000000u | (unsigned)((int)bits >> 31));
  bool pred = fk <= thresh_hi;     // superset of exact u64 test; flush is exact
  ull mask = __ballot(pred);
  if (mask) {
    int pos = cnt + (int)__builtin_amdgcn_mbcnt_hi(
                        (unsigned)(mask >> 32),
                        __builtin_amdgcn_mbcnt_lo((unsigned)mask, 0u));
    if (pred) buf[pos] = ((ull)fk << 32) | idx32;
    cnt += __popcll(mask);
    if (cnt >= 64) {
      ull v = buf[lane];
      v = bitonic_sort64(v, lane);
      ull vr = __shfl(v, 63 - lane);
      R = minu64(R, vr);
      R = bitonic_merge64(R, lane);
      thresh_hi = (unsigned)__shfl((int)(unsigned)(R >> 32), 15);
      cnt -= 64;
      if (lane < cnt) {
        ull tmp = buf[64 + lane];
        buf[lane] = tmp;
      }
    }
  }
}

__device__ __forceinline__ ull final_flush(ull R, int cnt, ull* buf, int lane) {
  ull v = (lane < cnt) ? buf[lane] : ~0ull;
  v = bitonic_sort64(v, lane);
  ull vr = __shfl(v, 63 - lane);
  R = minu64(R, vr);
  return bitonic_merge64(R, lane);
}

// MEGA kernel v12 restored byte-identical (mega ~76us by subtraction in
// R10/R11; R12's 4q/wave variant regressed to ~84 — 2q/wave is the optimum:
// candidate-load amortization without over-lengthening the dependent chain).
//   blocks [0,2048):    KNN, 8 queries/block (dispatched FIRST, long pole)
//   blocks [2048,4096): P/Q, 2 points/wave (backfills knn's ragged tail)
//   blocks [4096,4145): W1/W2/bias fold for mlp
__global__ __launch_bounds__(256) void mega_kernel(
    const float* __restrict__ xyz, const float* __restrict__ points,
    const float* __restrict__ w0, const float* __restrict__ b0, const float* __restrict__ g0,
    const float* __restrict__ be0, const float* __restrict__ rm0, const float* __restrict__ rv0,
    const float* __restrict__ w1, const float* __restrict__ b1, const float* __restrict__ g1,
    const float* __restrict__ be1, const float* __restrict__ rm1, const float* __restrict__ rv1,
    const float* __restrict__ w2, const float* __restrict__ b2, const float* __restrict__ g2,
    const float* __restrict__ be2, const float* __restrict__ rm2, const float* __restrict__ rv2,
    float* __restrict__ ws, int* __restrict__ knnOut) {
  __shared__ __align__(16) unsigned char smem[20480];  // knn: 8K flush bufs; pq: 17.2K w0
  int blk = blockIdx.x;
  int tid = threadIdx.x;

  if (blk < 2048) {
    // ---------------- KNN: 2 queries/wave, register-direct candidates -----
    ull* bufb = (ull*)smem;                       // [4 waves][2 queries][128]
    int lane = tid & 63, w = tid >> 6;
    int b = blk >> 9;                             // 512 blocks per batch
    int n0 = ((blk & 511) << 3) + (w << 1);
    int n1 = n0 + 1;
    const float* xb = xyz + (size_t)b * NPT * 3;
    ull* buf0 = bufb + w * 256;
    ull* buf1 = buf0 + 128;

    float4 q0, q1;
    {
      const float* qp = xb + n0 * 3;
      float ax = qp[0], ay = qp[1], az = qp[2];
      float bx = qp[3], by = qp[4], bz = qp[5];
      q0 = make_float4(ax, ay, az,
          __fadd_rn(__fadd_rn(__fmul_rn(ax, ax), __fmul_rn(ay, ay)), __fmul_rn(az, az)));
      q1 = make_float4(bx, by, bz,
          __fadd_rn(__fadd_rn(__fmul_rn(bx, bx), __fmul_rn(by, by)), __fmul_rn(bz, bz)));
    }
    ull R0 = ~0ull, R1 = ~0ull;
    unsigned th0 = 0xFFFFFFFFu, th1 = 0xFFFFFFFFu;
    int cnt0 = 0, cnt1 = 0;

    // iter-0 preload (lane-resident candidate)
    float cx = xb[3 * lane], cy = xb[3 * lane + 1], cz = xb[3 * lane + 2];
#pragma unroll 1
    for (int g = 0; g < NPT; g += 64) {
      // prefetch next group (wrapped on last iter; values unused)
      int ni = 3 * ((g + 64 + lane) & (NPT - 1));
      float nx = xb[ni], ny = xb[ni + 1], nz = xb[ni + 2];
      float csq = __fadd_rn(__fadd_rn(__fmul_rn(cx, cx), __fmul_rn(cy, cy)),
                            __fmul_rn(cz, cz));
      float4 c = make_float4(cx, cy, cz, csq);
      unsigned idx32 = (unsigned)(g + lane);
      filter_step(q0, c, idx32, th0, cnt0, R0, buf0, lane);
      filter_step(q1, c, idx32, th1, cnt1, R1, buf1, lane);
      cx = nx; cy = ny; cz = nz;
    }
    R0 = final_flush(R0, cnt0, buf0, lane);
    R1 = final_flush(R1, cnt1, buf1, lane);
    if (lane < KNN_K) {
      knnOut[(b * NPT + n0) * KNN_K + lane] = (int)(unsigned)(R0 & 0xFFFFFFFFull);
      knnOut[(b * NPT + n1) * KNN_K + lane] = (int)(unsigned)(R1 & 0xFFFFFFFFull);
    }
    return;
  }

  if (blk < 4096) {
    // ---------------- P/Q precompute: 2 points per wave ------------------
    float* wlds = (float*)smem;                   // [64*67] folded w0
    for (int j = tid; j < 4288; j += 256) {
      int r = j / 67;
      float s = g0[r] * rsqrtf(rv0[r] + EPSV);
      wlds[j] = __fmul_rn(w0[j], s);
    }
    __syncthreads();
    int oc = tid & 63;
    int base = (blk - 2048) * 8 + (tid >> 6);
    float s = g0[oc] * rsqrtf(rv0[oc] + EPSV);
    float b0f = (b0[oc] - rm0[oc]) * s + be0[oc];
    const float* wrow = wlds + oc * 67;           // stride-67 -> 2-way bank (free)
#pragma unroll 1
    for (int pt = 0; pt < 2; ++pt) {
      int i = base + pt * 4;
      float x = xyz[i * 3], y = xyz[i * 3 + 1], z = xyz[i * 3 + 2];
      float qacc = wrow[0] * x;
      qacc = fmaf(wrow[1], y, qacc);
      qacc = fmaf(wrow[2], z, qacc);
      float acc = b0f + qacc;
      const float* prow = points + (size_t)i * 64;
#pragma unroll 4
      for (int c = 0; c < 64; ++c) acc = fmaf(wrow[3 + c], prow[c], acc);
      ws[P_OFF + (size_t)i * 64 + oc] = acc;
      ws[Q_OFF + (size_t)i * 64 + oc] = qacc;
    }
    return;
  }

  // ---------------- weight fold for mlp (W1T/B1/W2T/B2) ------------------
  {
    int i = (blk - 4096) * 256 + tid + 4352;
    if (i < 8448) {
      int j = i - 4352; int oc = j & 63, ic = j >> 6;
      float s = g1[oc] * rsqrtf(rv1[oc] + EPSV);
      ws[i] = w1[oc * 64 + ic] * s;
    } else if (i < 8512) {
      int oc = i - 8448;
      float s = g1[oc] * rsqrtf(rv1[oc] + EPSV);
      ws[i] = (b1[oc] - rm1[oc]) * s + be1[oc];
    } else if (i < 16704) {
      int j = i - 8512; int ic = j >> 7, oc = j & 127;
      float s = g2[oc] * rsqrtf(rv2[oc] + EPSV);
      ws[i] = w2[oc * 64 + ic] * s;               // w2t [ic][oc]
    } else if (i < 16832) {
      int oc = i - 16704;
      float s = g2[oc] * rsqrtf(rv2[oc] + EPSV);
      ws[i] = (b2[oc] - rm2[oc]) * s + be2[oc];
    }
  }
}

// MLP v14 kept byte-identical (86.0us measured in R12, passed): v8 structure
// (40 KB LDS, 4 blocks/CU) + distance-2 software-pipelined GEMM inner loop.
// VALU now ~saturated (derived VALUBusy >100% = co-issue counting); ~1.1x
// above pure-FMA floor. Accumulation order bias + ic 0..63 -> bit-identical.
__global__ __launch_bounds__(256, 4) void mlp_kernel(
    const float* __restrict__ wbuf, const int* __restrict__ knn,
    float* __restrict__ out) {
  __shared__ __align__(16) float Ash[64 * 128];   // 32 KB [ic][p]
  __shared__ __align__(16) float Wsh[32 * 64];    // 8 KB chunk [icLocal][oc]
  int tid = threadIdx.x;
  int qblk = blockIdx.x << 3;                     // 8 flat queries per block

  const float4* w1g = (const float4*)(wbuf + W1T_OFF);   // [64][16 f4]
  const float4* w2g = (const float4*)(wbuf + W2T_OFF);   // [64][32 f4]
  float4* wl = (float4*)Wsh;

  // W2 chunk (pass p, ic-half h) entry e in [0,512): row 32h+(e>>4), colf4 16p+(e&15)
#define W2IDX(e, p, h) ((((h) << 5) + ((e) >> 4)) * 32 + ((p) << 4) + ((e) & 15))

  // ---- preload W1a ----
  float4 s0 = w1g[tid];
  float4 s1 = w1g[256 + tid];

  // ---- h0: pair p = tid&127, ic-half = tid>>7 ----
  {
    int p = tid & 127, half = tid >> 7;
    int q = qblk + (p >> 4);
    int k = p & 15;
    int src = knn[q * KNN_K + k];                 // coalesced across 128 threads
    int srow = (q & ~(NPT - 1)) + src;
    const float4* Pp = (const float4*)(wbuf + P_OFF + (size_t)srow * 64 + half * 32);
    const float4* Qp = (const float4*)(wbuf + Q_OFF + (size_t)q * 64 + half * 32);
#pragma unroll
    for (int j = 0; j < 8; ++j) {
      float4 pv = Pp[j];
      float4 qv = Qp[j];
      int ic = half * 32 + j * 4;
      Ash[(ic + 0) * 128 + p] = fmaxf(pv.x - qv.x, 0.0f);
      Ash[(ic + 1) * 128 + p] = fmaxf(pv.y - qv.y, 0.0f);
      Ash[(ic + 2) * 128 + p] = fmaxf(pv.z - qv.z, 0.0f);
      Ash[(ic + 3) * 128 + p] = fmaxf(pv.w - qv.w, 0.0f);
    }
  }
  // write W1a; preload W1b
  wl[tid] = s0; wl[256 + tid] = s1;
  s0 = w1g[512 + tid]; s1 = w1g[768 + tid];
  __syncthreads();                                 // S1: h0 + W1a visible

  int og = tid & 7, pg = tid >> 3;                 // 32 pgrp x 8 ogrp
  const float* Arow = Ash + 4 * pg;
  const float* Wrow = Wsh + 8 * og;
  float acc[4][8];                                 // [pair][oc]

  // distance-2 software-pipelined 32-ic GEMM: loads for ic+2 issue before
  // the FMAs of ic; all register names static after full unroll.
#define LD_A(R0, i)  (*(const float4*)(Arow + ((R0) + (i)) * 128))
#define LD_W0(i)     (*(const float4*)(Wrow + (i) * 64))
#define LD_W1(i)     (*(const float4*)(Wrow + (i) * 64 + 4))
#define GEMM32(R0)                                                        \
  {                                                                       \
    float4 aA = LD_A(R0, 0), wA0 = LD_W0(0), wA1 = LD_W1(0);              \
    float4 aB = LD_A(R0, 1), wB0 = LD_W0(1), wB1 = LD_W1(1);              \
    _Pragma("unroll")                                                     \
    for (int ic = 0; ic < 32; ++ic) {                                     \
      int nx = (ic + 2 <= 31) ? ic + 2 : 31;                              \
      float4 aN = LD_A(R0, nx);                                           \
      float4 wN0 = LD_W0(nx);                                             \
      float4 wN1 = LD_W1(nx);                                             \
      float av[4] = {aA.x, aA.y, aA.z, aA.w};                             \
      float wv[8] = {wA0.x, wA0.y, wA0.z, wA0.w, wA1.x, wA1.y, wA1.z, wA1.w};\
      _Pragma("unroll")                                                   \
      for (int ii = 0; ii < 4; ++ii)                                      \
        _Pragma("unroll")                                                 \
        for (int jj = 0; jj < 8; ++jj) acc[ii][jj] = fmaf(av[ii], wv[jj], acc[ii][jj]); \
      aA = aB; wA0 = wB0; wA1 = wB1;                                      \
      aB = aN; wB0 = wN0; wB1 = wN1;                                      \
    }                                                                     \
  }

  // ---- layer 1 ----
  {
    float4 b0v = *(const float4*)(wbuf + B1_OFF + 8 * og);
    float4 b1v = *(const float4*)(wbuf + B1_OFF + 8 * og + 4);
    float bj[8] = {b0v.x, b0v.y, b0v.z, b0v.w, b1v.x, b1v.y, b1v.z, b1v.w};
#pragma unroll
    for (int i = 0; i < 4; ++i)
#pragma unroll
      for (int j = 0; j < 8; ++j) acc[i][j] = bj[j];
  }
  GEMM32(0)                                        // W1a: ic 0..31
  __syncthreads();                                 // S2: W1a reads done
  wl[tid] = s0; wl[256 + tid] = s1;                // write W1b
  s0 = w2g[W2IDX(tid, 0, 0)]; s1 = w2g[W2IDX(tid + 256, 0, 0)];
  __syncthreads();                                 // S3: W1b visible
  GEMM32(32)                                       // W1b: ic 32..63
  __syncthreads();                                 // S4: all Ash(h0)+W1b reads done

  // h1 -> A[oc][p] (write throughput-limited, once per layer: accepted)
#pragma unroll
  for (int j = 0; j < 8; ++j) {
    int oc = 8 * og + j;
    *(float4*)(Ash + oc * 128 + 4 * pg) =
        make_float4(fmaxf(acc[0][j], 0.0f), fmaxf(acc[1][j], 0.0f),
                    fmaxf(acc[2][j], 0.0f), fmaxf(acc[3][j], 0.0f));
  }
  // stage W2p0a from regs; preload W2p0b
  wl[tid] = s0; wl[256 + tid] = s1;
  s0 = w2g[W2IDX(tid, 0, 1)]; s1 = w2g[W2IDX(tid + 256, 0, 1)];
  __syncthreads();                                 // S5: h1 + W2p0a visible

  int qout = qblk + (pg >> 2);
  float* obase = out + (size_t)qout * 128 + 8 * og;

  // ---- layer 2 pass 0 (oc 0..63) ----
  {
    float4 b0v = *(const float4*)(wbuf + B2_OFF + 8 * og);
    float4 b1v = *(const float4*)(wbuf + B2_OFF + 8 * og + 4);
    float bj[8] = {b0v.x, b0v.y, b0v.z, b0v.w, b1v.x, b1v.y, b1v.z, b1v.w};
#pragma unroll
    for (int i = 0; i < 4; ++i)
#pragma unroll
      for (int j = 0; j < 8; ++j) acc[i][j] = bj[j];
  }
  GEMM32(0)                                        // W2p0a: ic 0..31
  __syncthreads();                                 // S6
  wl[tid] = s0; wl[256 + tid] = s1;                // write W2p0b
  s0 = w2g[W2IDX(tid, 1, 0)]; s1 = w2g[W2IDX(tid + 256, 1, 0)];
  __syncthreads();                                 // S7
  GEMM32(32)                                       // W2p0b: ic 32..63
  {
    float m[8];
#pragma unroll
    for (int j = 0; j < 8; ++j) {
      float v = fmaxf(fmaxf(acc[0][j], acc[1][j]), fmaxf(acc[2][j], acc[3][j]));
      v = fmaxf(v, 0.0f);
      v = fmaxf(v, __shfl_xor(v, 8));              // pg bit 0
      m[j] = fmaxf(v, __shfl_xor(v, 16));          // pg bit 1
    }
    if ((pg & 3) == 0) {
      *(float4*)(obase)     = make_float4(m[0], m[1], m[2], m[3]);
      *(float4*)(obase + 4) = make_float4(m[4], m[5], m[6], m[7]);
    }
  }
  __syncthreads();                                 // S8
  wl[tid] = s0; wl[256 + tid] = s1;                // write W2p1a
  s0 = w2g[W2IDX(tid, 1, 1)]; s1 = w2g[W2IDX(tid + 256, 1, 1)];
  __syncthreads();                                 // S9

  // ---- layer 2 pass 1 (oc 64..127) ----
  {
    float4 b0v = *(const float4*)(wbuf + B2_OFF + 64 + 8 * og);
    float4 b1v = *(const float4*)(wbuf + B2_OFF + 64 + 8 * og + 4);
    float bj[8] = {b0v.x, b0v.y, b0v.z, b0v.w, b1v.x, b1v.y, b1v.z, b1v.w};
#pragma unroll
    for (int i = 0; i < 4; ++i)
#pragma unroll
      for (int j = 0; j < 8; ++j) acc[i][j] = bj[j];
  }
  GEMM32(0)                                        // W2p1a: ic 0..31
  __syncthreads();                                 // S10
  wl[tid] = s0; wl[256 + tid] = s1;                // write W2p1b
  __syncthreads();                                 // S11
  GEMM32(32)                                       // W2p1b: ic 32..63
  {
    float m[8];
#pragma unroll
    for (int j = 0; j < 8; ++j) {
      float v = fmaxf(fmaxf(acc[0][j], acc[1][j]), fmaxf(acc[2][j], acc[3][j]));
      v = fmaxf(v, 0.0f);
      v = fmaxf(v, __shfl_xor(v, 8));
      m[j] = fmaxf(v, __shfl_xor(v, 16));
    }
    if ((pg & 3) == 0) {
      *(float4*)(obase + 64)     = make_float4(m[0], m[1], m[2], m[3]);
      *(float4*)(obase + 64 + 4) = make_float4(m[4], m[5], m[6], m[7]);
    }
  }
#undef GEMM32
#undef LD_A
#undef LD_W0
#undef LD_W1
#undef W2IDX
}

extern "C" void kernel_launch(void* const* d_in, const int* in_sizes, int n_in,
                              void* d_out, int out_size, void* d_ws, size_t ws_size,
                              hipStream_t stream) {
  const float* xyz    = (const float*)d_in[0];
  const float* points = (const float*)d_in[1];
  float* wsF = (float*)d_ws;
  int* idxBuf = (int*)(wsF + IDX_OFF);

  mega_kernel<<<4145, 256, 0, stream>>>(
      xyz, points,
      (const float*)d_in[2],  (const float*)d_in[3],  (const float*)d_in[4],
      (const float*)d_in[5],  (const float*)d_in[6],  (const float*)d_in[7],
      (const float*)d_in[8],  (const float*)d_in[9],  (const float*)d_in[10],
      (const float*)d_in[11], (const float*)d_in[12], (const float*)d_in[13],
      (const float*)d_in[14], (const float*)d_in[15], (const float*)d_in[16],
      (const float*)d_in[17], (const float*)d_in[18], (const float*)d_in[19],
      wsF, idxBuf);
  mlp_kernel<<<2048, 256, 0, stream>>>(wsF, idxBuf, (float*)d_out);
}